// Round 4
// baseline (153.387 us; speedup 1.0000x reference)
//
#include <hip/hip_runtime.h>
#include <hip/hip_bf16.h>

typedef __attribute__((ext_vector_type(8))) short short8;
typedef __attribute__((ext_vector_type(4))) float f32x4;

#define NROW 8192
#define FDIM 64
#define INDIM 128
#define BK 64
#define BM 128       // rows per block in k_main (4 waves x 32 rows)
#define NW (NROW / 64)  // 128 mask words per row
#define MBOUND 48.0f // static softmax-shift bound (validated R3): overflow needs dmax>136
#define L2E 1.44269504f

static __device__ __forceinline__ short bfb(float x) {
  __hip_bfloat16 b = __float2bfloat16(x);
  return *reinterpret_cast<short*>(&b);
}
static __device__ __forceinline__ float lrelu(float x) { return fmaxf(x, 0.01f * x); }

// ---------------- Kernel 0: pack adj (256 MB int32 0/1) into bitmasks Ab[8192][128] (8 MB) --------
// One wave per row. dwordx4 loads (16 B/lane): lane l covers cols 4l..4l+3 of each 256-col group.
// Nibble per lane -> 32-bit OR-tree within 8-lane clusters -> linear-order uint64 words.
__global__ __launch_bounds__(256) void k_pack(const int* __restrict__ adj,
                                              unsigned long long* __restrict__ Ab) {
  const int row = blockIdx.x * 4 + (threadIdx.x >> 6);
  const int l = threadIdx.x & 63;
  const int4* p = (const int4*)(adj + (size_t)row * NROW) + l;
  const int lsh = 4 * (l & 7);
  unsigned long long* abr = Ab + (size_t)row * NW;
#pragma unroll 8
  for (int it = 0; it < NROW / 256; ++it) {
    int4 v = p[it * 64];
    unsigned int nib = (unsigned int)((v.x & 1) | ((v.y & 1) << 1) | ((v.z & 1) << 2) | ((v.w & 1) << 3));
    unsigned int val = nib << lsh;
    val |= __shfl_xor(val, 1, 64);
    val |= __shfl_xor(val, 2, 64);
    val |= __shfl_xor(val, 4, 64);
    unsigned int hi = __shfl_xor(val, 8, 64);  // partner cluster holds the high dword
    if ((l & 15) == 0)
      abr[it * 4 + (l >> 4)] = (unsigned long long)val | ((unsigned long long)hi << 32);
  }
}

// ---------------- Kernel 1: Wh = h@W (f32), WhT (bf16, f-major), s = Wh@a1, d = Wh@a2 ----------------
__global__ __launch_bounds__(256) void k_wh(const float* __restrict__ h,
                                            const float* __restrict__ W,
                                            const float* __restrict__ a,
                                            __hip_bfloat16* __restrict__ WhT,
                                            float* __restrict__ s,
                                            float* __restrict__ d) {
  const int i = blockIdx.x * 4 + (threadIdx.x >> 6);  // row, one wave per row
  const int f = threadIdx.x & 63;                     // feature, lane
  const float* hrow = h + (size_t)i * INDIM;
  float acc = 0.f;
#pragma unroll 8
  for (int k = 0; k < INDIM; ++k) acc = fmaf(hrow[k], W[k * FDIM + f], acc);
  WhT[(size_t)f * NROW + i] = __float2bfloat16(acc);
  float p1 = acc * a[f];
  float p2 = acc * a[FDIM + f];
#pragma unroll
  for (int m = 32; m; m >>= 1) {
    p1 += __shfl_xor(p1, m, 64);
    p2 += __shfl_xor(p2, m, 64);
  }
  if (f == 0) { s[i] = p1; d[i] = p2; }
}

// ---------------- Kernel 2: fused masked-softmax-attention (mask-driven, barrier/LDS-free) --------
__global__ __launch_bounds__(256, 4) void k_main(const unsigned long long* __restrict__ Ab,
                                                 const __hip_bfloat16* __restrict__ WhT,
                                                 const float* __restrict__ sArr,
                                                 const float* __restrict__ dArr,
                                                 float* __restrict__ accp,
                                                 float* __restrict__ Zp,
                                                 int splits) {
  const int t = threadIdx.x;
  const int w = t >> 6, l = t & 63;
  const int lr = l & 15;  // fragment row index
  const int lk = l >> 4;  // k-group 0..3
  const int panel = blockIdx.x / splits;
  const int split = blockIdx.x - panel * splits;
  const int row0 = panel * BM + w * 32;
  const int jspan = NROW / splits;
  const int j0 = split * jspan;
  const int nchunk = jspan / BK;

  const float s0 = sArr[row0 + lr];
  const float s1 = sArr[row0 + 16 + lr];
  const float sm0 = -lrelu(s0 + MBOUND) * L2E;  // -m0*log2(e)
  const float sm1 = -lrelu(s1 + MBOUND) * L2E;

  f32x4 acc[2][4];
#pragma unroll
  for (int ri = 0; ri < 2; ++ri)
#pragma unroll
    for (int nf = 0; nf < 4; ++nf) acc[ri][nf] = (f32x4){0.f, 0.f, 0.f, 0.f};
  float z0 = 0.f, z1 = 0.f;

  const unsigned long long* ab0 = Ab + (size_t)(row0 + lr) * NW + j0 / 64;
  const unsigned long long* ab1 = ab0 + (size_t)16 * NW;
  const float* dp = dArr + j0 + lk * 8;
  const __hip_bfloat16* bbase = WhT + (size_t)lr * NROW + j0 + lk * 8;

  for (int c = 0; c < nchunk; ++c) {
    const int off = c * BK;
    const unsigned long long M0 = ab0[c];
    const unsigned long long M1 = ab1[c];

#pragma unroll
    for (int ks = 0; ks < 2; ++ks) {
      const int jo = off + ks * 32;
      const unsigned int y0 = (unsigned int)(M0 >> (ks * 32 + lk * 8)) & 0xffu;
      const unsigned int y1 = (unsigned int)(M1 >> (ks * 32 + lk * 8)) & 0xffu;

      // B fragments: direct global loads (WhT is 1 MB, L2-resident)
      short8 b0 = *(const short8*)(bbase + jo);
      short8 b1 = *(const short8*)(bbase + jo + 16 * NROW);
      short8 b2 = *(const short8*)(bbase + jo + 32 * NROW);
      short8 b3 = *(const short8*)(bbase + jo + 48 * NROW);

      float4 dv0 = *(const float4*)(dp + jo);
      float4 dv1 = *(const float4*)(dp + jo + 4);
      float dj[8] = {dv0.x, dv0.y, dv0.z, dv0.w, dv1.x, dv1.y, dv1.z, dv1.w};

      short8 pa0, pa1;
#pragma unroll
      for (int q = 0; q < 8; ++q) {
        const float dq = dj[q];
        float e0 = exp2f(fmaf(lrelu(s0 + dq), L2E, sm0));
        float e1 = exp2f(fmaf(lrelu(s1 + dq), L2E, sm1));
        float w0 = ((y0 >> q) & 1u) ? e0 : 0.f;
        float w1 = ((y1 >> q) & 1u) ? e1 : 0.f;
        z0 += w0;
        z1 += w1;
        pa0[q] = bfb(w0);
        pa1[q] = bfb(w1);
      }

      acc[0][0] = __builtin_amdgcn_mfma_f32_16x16x32_bf16(pa0, b0, acc[0][0], 0, 0, 0);
      acc[0][1] = __builtin_amdgcn_mfma_f32_16x16x32_bf16(pa0, b1, acc[0][1], 0, 0, 0);
      acc[0][2] = __builtin_amdgcn_mfma_f32_16x16x32_bf16(pa0, b2, acc[0][2], 0, 0, 0);
      acc[0][3] = __builtin_amdgcn_mfma_f32_16x16x32_bf16(pa0, b3, acc[0][3], 0, 0, 0);
      acc[1][0] = __builtin_amdgcn_mfma_f32_16x16x32_bf16(pa1, b0, acc[1][0], 0, 0, 0);
      acc[1][1] = __builtin_amdgcn_mfma_f32_16x16x32_bf16(pa1, b1, acc[1][1], 0, 0, 0);
      acc[1][2] = __builtin_amdgcn_mfma_f32_16x16x32_bf16(pa1, b2, acc[1][2], 0, 0, 0);
      acc[1][3] = __builtin_amdgcn_mfma_f32_16x16x32_bf16(pa1, b3, acc[1][3], 0, 0, 0);
    }
  }

  // Z: sum the 4 k-groups (lanes lr, lr+16, lr+32, lr+48 hold partials of row lr)
  z0 += __shfl_xor(z0, 16, 64);
  z0 += __shfl_xor(z0, 32, 64);
  z1 += __shfl_xor(z1, 16, 64);
  z1 += __shfl_xor(z1, 32, 64);
  if (l < 16) {
    Zp[(size_t)blockIdx.x * BM + w * 32 + lr] = z0;
    Zp[(size_t)blockIdx.x * BM + w * 32 + 16 + lr] = z1;
  }

  // store partial acc tile: row = w*32 + ri*16 + lk*4 + q, col = nf*16 + lr
  float* ab = accp + (size_t)blockIdx.x * (BM * 64);
#pragma unroll
  for (int ri = 0; ri < 2; ++ri)
#pragma unroll
    for (int nf = 0; nf < 4; ++nf)
#pragma unroll
      for (int q = 0; q < 4; ++q)
        ab[(w * 32 + ri * 16 + lk * 4 + q) * 64 + nf * 16 + lr] = acc[ri][nf][q];
}

// ---------------- Kernel 3: combine partials, normalize, elu ----------------
__global__ __launch_bounds__(256) void k_combine(const float* __restrict__ accp,
                                                 const float* __restrict__ Zp,
                                                 float* __restrict__ out,
                                                 int splits) {
  const int idx = blockIdx.x * 256 + threadIdx.x;
  const int r = idx >> 6, f = idx & 63;
  const int panel = r >> 7, rl = r & 127;
  float sum = 0.f, z = 0.f;
  for (int sp = 0; sp < splits; ++sp) {
    const int b = panel * splits + sp;
    sum += accp[(size_t)b * (BM * 64) + rl * 64 + f];
    z += Zp[(size_t)b * BM + rl];
  }
  const float v = sum / z;
  out[idx] = (v > 0.f) ? v : expm1f(v);
}

extern "C" void kernel_launch(void* const* d_in, const int* in_sizes, int n_in,
                              void* d_out, int out_size, void* d_ws, size_t ws_size,
                              hipStream_t stream) {
  const float* h = (const float*)d_in[0];
  const int* adj = (const int*)d_in[1];
  const float* W = (const float*)d_in[2];
  const float* a = (const float*)d_in[3];
  float* out = (float*)d_out;

  const int npanel = NROW / BM;  // 64
  int splits = 16;
  auto need = [&](int sp) -> size_t {
    return (size_t)1048576 /*WhT*/ + 65536 /*s,d*/ +
           (size_t)sp * npanel * BM * 4 /*Zp*/ +
           (size_t)sp * npanel * (BM * 64) * 4 /*accp*/ +
           (size_t)NROW * NW * 8 /*Ab*/;
  };
  while (splits > 1 && need(splits) > ws_size) splits >>= 1;

  char* p = (char*)d_ws;
  __hip_bfloat16* WhT = (__hip_bfloat16*)p;
  float* s = (float*)(p + 1048576);
  float* d = (float*)(p + 1048576 + 32768);
  float* Zp = (float*)(p + 1048576 + 65536);
  float* accp = (float*)((char*)Zp + (size_t)splits * npanel * BM * 4);
  unsigned long long* Ab = (unsigned long long*)((char*)accp + (size_t)splits * npanel * (BM * 64) * 4);

  hipLaunchKernelGGL(k_pack, dim3(NROW / 4), dim3(256), 0, stream, adj, Ab);
  hipLaunchKernelGGL(k_wh, dim3(NROW / 4), dim3(256), 0, stream, h, W, a, WhT, s, d);
  hipLaunchKernelGGL(k_main, dim3(npanel * splits), dim3(256), 0, stream,
                     Ab, WhT, s, d, accp, Zp, splits);
  hipLaunchKernelGGL(k_combine, dim3(out_size / 256), dim3(256), 0, stream,
                     accp, Zp, out, splits);
}

// Round 5
// 140.465 us; speedup vs baseline: 1.0920x; 1.0920x over previous
//
#include <hip/hip_runtime.h>
#include <hip/hip_bf16.h>

typedef __attribute__((ext_vector_type(8))) short short8;
typedef __attribute__((ext_vector_type(4))) float f32x4;
typedef __attribute__((ext_vector_type(4))) int i32x4;

#define NROW 8192
#define FDIM 64
#define INDIM 128
#define BM 128        // rows per block in k_main (4 waves x 32 rows)
#define SPLITS 8
#define MBOUND 48.0f  // static softmax-shift bound (validated R3/R4)
#define L2E 1.44269504f

static __device__ __forceinline__ short bfb(float x) {
  __hip_bfloat16 b = __float2bfloat16(x);
  return *reinterpret_cast<short*>(&b);
}
static __device__ __forceinline__ float lrelu(float x) { return fmaxf(x, 0.01f * x); }

// ---------------- Kernel 0: pack adj (256 MB) -> Ab bitmasks, column-block-major (8 MB) ----------
// One wave per row, 16 iters x 512 cols. Lane l covers cols 8l..8l+7 per window via 2 nontemporal
// dwordx4 loads; packs a byte in-lane (no cross-lane ops). Word layout: word (span*64+l) covers
// cols span*4096 + it8*512 + 8l..+7 at bits 8*it8+m. Stored Ab[word][row] (row-major inner) so
// k_main's per-row loads coalesce. XCD-aware row mapping keeps Ab lines written within one XCD.
__global__ __launch_bounds__(256) void k_pack(const int* __restrict__ adj,
                                              unsigned long long* __restrict__ Ab) {
  const int b = blockIdx.x;
  const int row = ((b & 7) << 10) + ((b >> 3) << 2) + (threadIdx.x >> 6);
  const int l = threadIdx.x & 63;
  const i32x4* p = (const i32x4*)(adj + (size_t)row * NROW) + 2 * l;
  unsigned long long W0 = 0ull, W1 = 0ull;
#pragma unroll
  for (int it = 0; it < 16; ++it) {
    i32x4 u = __builtin_nontemporal_load(p + (size_t)it * 128);
    i32x4 v = __builtin_nontemporal_load(p + (size_t)it * 128 + 1);
    unsigned int byte = (unsigned int)((u.x & 1) | ((u.y & 1) << 1) | ((u.z & 1) << 2) |
                                       ((u.w & 1) << 3) | ((v.x & 1) << 4) | ((v.y & 1) << 5) |
                                       ((v.z & 1) << 6) | ((v.w & 1) << 7));
    unsigned long long sh = (unsigned long long)byte << (8 * (it & 7));
    if (it < 8) W0 |= sh; else W1 |= sh;
  }
  Ab[(size_t)l * NROW + row] = W0;         // span 0 (cols 0..4095)
  Ab[(size_t)(64 + l) * NROW + row] = W1;  // span 1 (cols 4096..8191)
}

// ---------------- Kernel 1: Wh = h@W (f32), WhT (bf16, f-major), s = Wh@a1, d = Wh@a2 ------------
__global__ __launch_bounds__(256) void k_wh(const float* __restrict__ h,
                                            const float* __restrict__ W,
                                            const float* __restrict__ a,
                                            __hip_bfloat16* __restrict__ WhT,
                                            float* __restrict__ s,
                                            float* __restrict__ d) {
  const int i = blockIdx.x * 4 + (threadIdx.x >> 6);
  const int f = threadIdx.x & 63;
  const float* hrow = h + (size_t)i * INDIM;
  float acc = 0.f;
#pragma unroll 8
  for (int k = 0; k < INDIM; ++k) acc = fmaf(hrow[k], W[k * FDIM + f], acc);
  WhT[(size_t)f * NROW + i] = __float2bfloat16(acc);
  float p1 = acc * a[f];
  float p2 = acc * a[FDIM + f];
#pragma unroll
  for (int m = 32; m; m >>= 1) {
    p1 += __shfl_xor(p1, m, 64);
    p2 += __shfl_xor(p2, m, 64);
  }
  if (f == 0) { s[i] = p1; d[i] = p2; }
}

// ---------------- Kernel 2: fused masked-softmax-attention (mask-driven, barrier/LDS-free) -------
__global__ __launch_bounds__(256, 4) void k_main(const unsigned long long* __restrict__ Ab,
                                                 const __hip_bfloat16* __restrict__ WhT,
                                                 const float* __restrict__ sArr,
                                                 const float* __restrict__ dArr,
                                                 float* __restrict__ accp,
                                                 float* __restrict__ Zp) {
  const int t = threadIdx.x;
  const int w = t >> 6, l = t & 63;
  const int lr = l & 15;  // fragment row index
  const int lk = l >> 4;  // k-group 0..3
  const int panel = blockIdx.x / SPLITS;
  const int split = blockIdx.x - panel * SPLITS;
  const int row0 = panel * BM + w * 32;
  const int jspan = NROW / SPLITS;
  const int j0 = split * jspan;
  const int nchunk = jspan / 64;

  const float s0 = sArr[row0 + lr];
  const float s1 = sArr[row0 + 16 + lr];
  const float sm0 = -lrelu(s0 + MBOUND) * L2E;
  const float sm1 = -lrelu(s1 + MBOUND) * L2E;

  f32x4 acc[2][4];
#pragma unroll
  for (int ri = 0; ri < 2; ++ri)
#pragma unroll
    for (int nf = 0; nf < 4; ++nf) acc[ri][nf] = (f32x4){0.f, 0.f, 0.f, 0.f};
  float z0 = 0.f, z1 = 0.f;

  const float* dp = dArr + j0 + lk * 8;
  const __hip_bfloat16* bbase = WhT + (size_t)lr * NROW + j0 + lk * 8;

  for (int c = 0; c < nchunk; ++c) {
    const int off = c * 64;
#pragma unroll
    for (int ks = 0; ks < 2; ++ks) {
      const int jo = off + ks * 32;
      const int colbase = j0 + jo + lk * 8;
      const int widx = (colbase >> 12) * 64 + ((colbase & 511) >> 3);
      const int sh8 = 8 * ((colbase >> 9) & 7);
      const unsigned long long Wm0 = Ab[(size_t)widx * NROW + row0 + lr];
      const unsigned long long Wm1 = Ab[(size_t)widx * NROW + row0 + 16 + lr];
      const unsigned int y0 = (unsigned int)(Wm0 >> sh8) & 0xffu;
      const unsigned int y1 = (unsigned int)(Wm1 >> sh8) & 0xffu;

      short8 b0 = *(const short8*)(bbase + jo);
      short8 b1 = *(const short8*)(bbase + jo + 16 * NROW);
      short8 b2 = *(const short8*)(bbase + jo + 32 * NROW);
      short8 b3 = *(const short8*)(bbase + jo + 48 * NROW);

      float4 dv0 = *(const float4*)(dp + jo);
      float4 dv1 = *(const float4*)(dp + jo + 4);
      float dj[8] = {dv0.x, dv0.y, dv0.z, dv0.w, dv1.x, dv1.y, dv1.z, dv1.w};

      short8 pa0, pa1;
#pragma unroll
      for (int q = 0; q < 8; ++q) {
        const float dq = dj[q];
        float e0 = exp2f(fmaf(lrelu(s0 + dq), L2E, sm0));
        float e1 = exp2f(fmaf(lrelu(s1 + dq), L2E, sm1));
        float w0 = ((y0 >> q) & 1u) ? e0 : 0.f;
        float w1 = ((y1 >> q) & 1u) ? e1 : 0.f;
        z0 += w0;
        z1 += w1;
        pa0[q] = bfb(w0);
        pa1[q] = bfb(w1);
      }

      acc[0][0] = __builtin_amdgcn_mfma_f32_16x16x32_bf16(pa0, b0, acc[0][0], 0, 0, 0);
      acc[0][1] = __builtin_amdgcn_mfma_f32_16x16x32_bf16(pa0, b1, acc[0][1], 0, 0, 0);
      acc[0][2] = __builtin_amdgcn_mfma_f32_16x16x32_bf16(pa0, b2, acc[0][2], 0, 0, 0);
      acc[0][3] = __builtin_amdgcn_mfma_f32_16x16x32_bf16(pa0, b3, acc[0][3], 0, 0, 0);
      acc[1][0] = __builtin_amdgcn_mfma_f32_16x16x32_bf16(pa1, b0, acc[1][0], 0, 0, 0);
      acc[1][1] = __builtin_amdgcn_mfma_f32_16x16x32_bf16(pa1, b1, acc[1][1], 0, 0, 0);
      acc[1][2] = __builtin_amdgcn_mfma_f32_16x16x32_bf16(pa1, b2, acc[1][2], 0, 0, 0);
      acc[1][3] = __builtin_amdgcn_mfma_f32_16x16x32_bf16(pa1, b3, acc[1][3], 0, 0, 0);
    }
  }

  z0 += __shfl_xor(z0, 16, 64);
  z0 += __shfl_xor(z0, 32, 64);
  z1 += __shfl_xor(z1, 16, 64);
  z1 += __shfl_xor(z1, 32, 64);
  if (l < 16) {
    Zp[(size_t)blockIdx.x * BM + w * 32 + lr] = z0;
    Zp[(size_t)blockIdx.x * BM + w * 32 + 16 + lr] = z1;
  }

  float* ab = accp + (size_t)blockIdx.x * (BM * 64);
#pragma unroll
  for (int ri = 0; ri < 2; ++ri)
#pragma unroll
    for (int nf = 0; nf < 4; ++nf)
#pragma unroll
      for (int q = 0; q < 4; ++q)
        ab[(w * 32 + ri * 16 + lk * 4 + q) * 64 + nf * 16 + lr] = acc[ri][nf][q];
}

// ---------------- Kernel 3: combine partials, normalize, elu ----------------
__global__ __launch_bounds__(256) void k_combine(const float* __restrict__ accp,
                                                 const float* __restrict__ Zp,
                                                 float* __restrict__ out) {
  const int idx = blockIdx.x * 256 + threadIdx.x;
  const int r = idx >> 6, f = idx & 63;
  const int panel = r >> 7, rl = r & 127;
  float sum = 0.f, z = 0.f;
#pragma unroll
  for (int sp = 0; sp < SPLITS; ++sp) {
    const int b = panel * SPLITS + sp;
    sum += accp[(size_t)b * (BM * 64) + rl * 64 + f];
    z += Zp[(size_t)b * BM + rl];
  }
  const float v = sum / z;
  out[idx] = (v > 0.f) ? v : expm1f(v);
}

extern "C" void kernel_launch(void* const* d_in, const int* in_sizes, int n_in,
                              void* d_out, int out_size, void* d_ws, size_t ws_size,
                              hipStream_t stream) {
  const float* h = (const float*)d_in[0];
  const int* adj = (const int*)d_in[1];
  const float* W = (const float*)d_in[2];
  const float* a = (const float*)d_in[3];
  float* out = (float*)d_out;

  const int npanel = NROW / BM;            // 64
  const int nblk = npanel * SPLITS;        // 512

  char* p = (char*)d_ws;
  __hip_bfloat16* WhT = (__hip_bfloat16*)p;                     // 1 MB
  float* s = (float*)(p + 1048576);                             // 32 KB
  float* d = (float*)(p + 1048576 + 32768);                     // 32 KB
  float* Zp = (float*)(p + 1048576 + 65536);                    // nblk*BM*4 = 256 KB
  float* accp = (float*)((char*)Zp + (size_t)nblk * BM * 4);    // nblk*32KB = 16 MB
  unsigned long long* Ab =
      (unsigned long long*)((char*)accp + (size_t)nblk * (BM * 64) * 4);  // 8 MB

  hipLaunchKernelGGL(k_pack, dim3(NROW / 4), dim3(256), 0, stream, adj, Ab);
  hipLaunchKernelGGL(k_wh, dim3(NROW / 4), dim3(256), 0, stream, h, W, a, WhT, s, d);
  hipLaunchKernelGGL(k_main, dim3(nblk), dim3(256), 0, stream, Ab, WhT, s, d, accp, Zp);
  hipLaunchKernelGGL(k_combine, dim3(out_size / 256), dim3(256), 0, stream, accp, Zp, out);
}

// Round 6
// 116.789 us; speedup vs baseline: 1.3134x; 1.2027x over previous
//
#include <hip/hip_runtime.h>
#include <hip/hip_bf16.h>

typedef __attribute__((ext_vector_type(8))) short short8;
typedef __attribute__((ext_vector_type(4))) float f32x4;

#define NROW 8192
#define FDIM 64
#define INDIM 128
#define BM 128        // rows per k_main block (4 waves x 32 rows)
#define SPLITS 16
#define MBOUND 48.0f  // static softmax-shift bound (validated R3-R5)
#define L2E 1.44269504f

static __device__ __forceinline__ short bfb(float x) {
  __hip_bfloat16 b = __float2bfloat16(x);
  return *reinterpret_cast<short*>(&b);
}
static __device__ __forceinline__ float lrelu(float x) { return fmaxf(x, 0.01f * x); }

// ---------------- Kernel 1: Wh = h@W (f32), WhT (bf16, f-major), s = Wh@a1, d = Wh@a2 ------------
__global__ __launch_bounds__(256) void k_wh(const float* __restrict__ h,
                                            const float* __restrict__ W,
                                            const float* __restrict__ a,
                                            __hip_bfloat16* __restrict__ WhT,
                                            float* __restrict__ s,
                                            float* __restrict__ d) {
  const int i = blockIdx.x * 4 + (threadIdx.x >> 6);
  const int f = threadIdx.x & 63;
  const float* hrow = h + (size_t)i * INDIM;
  float acc = 0.f;
#pragma unroll 8
  for (int k = 0; k < INDIM; ++k) acc = fmaf(hrow[k], W[k * FDIM + f], acc);
  WhT[(size_t)f * NROW + i] = __float2bfloat16(acc);
  float p1 = acc * a[f];
  float p2 = acc * a[FDIM + f];
#pragma unroll
  for (int m = 32; m; m >>= 1) {
    p1 += __shfl_xor(p1, m, 64);
    p2 += __shfl_xor(p2, m, 64);
  }
  if (f == 0) { s[i] = p1; d[i] = p2; }
}

// ---------------- Kernel 2: fused masked-softmax-attention ----------------
// Single pass over adj (nontemporal, coalesced dword per lane -> __ballot -> per-lane
// fragment bits). Z computed by an extra all-ones-B MFMA (row sums of bf16 P).
// Partials written in bf16. Barrier-free, LDS-free.
__global__ __launch_bounds__(256) void k_main(const int* __restrict__ adj,
                                              const __hip_bfloat16* __restrict__ WhT,
                                              const float* __restrict__ sArr,
                                              const float* __restrict__ dArr,
                                              __hip_bfloat16* __restrict__ accp,
                                              float* __restrict__ Zp) {
  const int t = threadIdx.x;
  const int w = t >> 6, l = t & 63;
  const int lr = l & 15;  // fragment row index
  const int lk = l >> 4;  // k-group 0..3
  const int panel = blockIdx.x / SPLITS;
  const int split = blockIdx.x - panel * SPLITS;
  const int row0 = panel * BM + w * 32;
  const int jspan = NROW / SPLITS;  // 512
  const int j0 = split * jspan;
  const int nchunk = jspan / 64;    // 8

  const float s0 = sArr[row0 + lr];
  const float s1 = sArr[row0 + 16 + lr];
  const float sm0 = -lrelu(s0 + MBOUND) * L2E;
  const float sm1 = -lrelu(s1 + MBOUND) * L2E;

  f32x4 acc[2][4], accZ[2];
#pragma unroll
  for (int ri = 0; ri < 2; ++ri) {
    accZ[ri] = (f32x4){0.f, 0.f, 0.f, 0.f};
#pragma unroll
    for (int nf = 0; nf < 4; ++nf) acc[ri][nf] = (f32x4){0.f, 0.f, 0.f, 0.f};
  }

  short8 bones;
#pragma unroll
  for (int q = 0; q < 8; ++q) bones[q] = (short)0x3F80;  // bf16 1.0

  const int* adjp = adj + (size_t)row0 * NROW + j0 + l;  // lane l -> column j0+off+l
  const float* dp = dArr + j0 + lk * 8;
  const __hip_bfloat16* bbase = WhT + (size_t)lr * NROW + j0 + lk * 8;

  for (int c = 0; c < nchunk; ++c) {
    const int off = c * 64;

    // ---- coalesced nontemporal adj -> 2 x 64-bit masks (rows lr, lr+16) ----
    unsigned long long M0 = 0ull, M1 = 0ull;
    {
      int av[16];
#pragma unroll
      for (int r = 0; r < 16; ++r)
        av[r] = __builtin_nontemporal_load(adjp + (size_t)r * NROW + off);
#pragma unroll
      for (int r = 0; r < 16; ++r) {
        unsigned long long b = __ballot(av[r] > 0);
        M0 = (lr == r) ? b : M0;
      }
#pragma unroll
      for (int r = 0; r < 16; ++r)
        av[r] = __builtin_nontemporal_load(adjp + (size_t)(16 + r) * NROW + off);
#pragma unroll
      for (int r = 0; r < 16; ++r) {
        unsigned long long b = __ballot(av[r] > 0);
        M1 = (lr == r) ? b : M1;
      }
    }

#pragma unroll
    for (int ks = 0; ks < 2; ++ks) {
      const int jo = off + ks * 32;
      const unsigned int y0 = (unsigned int)(M0 >> (ks * 32 + lk * 8)) & 0xffu;
      const unsigned int y1 = (unsigned int)(M1 >> (ks * 32 + lk * 8)) & 0xffu;

      short8 b0 = *(const short8*)(bbase + jo);
      short8 b1 = *(const short8*)(bbase + jo + 16 * NROW);
      short8 b2 = *(const short8*)(bbase + jo + 32 * NROW);
      short8 b3 = *(const short8*)(bbase + jo + 48 * NROW);

      float dj[8];
      *(float4*)&dj[0] = *(const float4*)(dp + jo);
      *(float4*)&dj[4] = *(const float4*)(dp + jo + 4);

      short8 pa0, pa1;
#pragma unroll
      for (int q = 0; q < 8; ++q) {
        const float dq = dj[q];
        float e0 = exp2f(fmaf(lrelu(s0 + dq), L2E, sm0));
        float e1 = exp2f(fmaf(lrelu(s1 + dq), L2E, sm1));
        pa0[q] = bfb(((y0 >> q) & 1u) ? e0 : 0.f);
        pa1[q] = bfb(((y1 >> q) & 1u) ? e1 : 0.f);
      }

      acc[0][0] = __builtin_amdgcn_mfma_f32_16x16x32_bf16(pa0, b0, acc[0][0], 0, 0, 0);
      acc[0][1] = __builtin_amdgcn_mfma_f32_16x16x32_bf16(pa0, b1, acc[0][1], 0, 0, 0);
      acc[0][2] = __builtin_amdgcn_mfma_f32_16x16x32_bf16(pa0, b2, acc[0][2], 0, 0, 0);
      acc[0][3] = __builtin_amdgcn_mfma_f32_16x16x32_bf16(pa0, b3, acc[0][3], 0, 0, 0);
      accZ[0]   = __builtin_amdgcn_mfma_f32_16x16x32_bf16(pa0, bones, accZ[0], 0, 0, 0);
      acc[1][0] = __builtin_amdgcn_mfma_f32_16x16x32_bf16(pa1, b0, acc[1][0], 0, 0, 0);
      acc[1][1] = __builtin_amdgcn_mfma_f32_16x16x32_bf16(pa1, b1, acc[1][1], 0, 0, 0);
      acc[1][2] = __builtin_amdgcn_mfma_f32_16x16x32_bf16(pa1, b2, acc[1][2], 0, 0, 0);
      acc[1][3] = __builtin_amdgcn_mfma_f32_16x16x32_bf16(pa1, b3, acc[1][3], 0, 0, 0);
      accZ[1]   = __builtin_amdgcn_mfma_f32_16x16x32_bf16(pa1, bones, accZ[1], 0, 0, 0);
    }
  }

  // ---- Z store: C/D row = lk*4+q, col = lr (all cols identical) ----
  if (lr == 0) {
    float* zb = Zp + (size_t)blockIdx.x * BM + w * 32;
#pragma unroll
    for (int q = 0; q < 4; ++q) {
      zb[lk * 4 + q] = accZ[0][q];
      zb[16 + lk * 4 + q] = accZ[1][q];
    }
  }

  // ---- partial acc tile (bf16): row = w*32 + ri*16 + lk*4 + q, col = nf*16 + lr ----
  __hip_bfloat16* ab = accp + (size_t)blockIdx.x * (BM * 64);
#pragma unroll
  for (int ri = 0; ri < 2; ++ri)
#pragma unroll
    for (int nf = 0; nf < 4; ++nf)
#pragma unroll
      for (int q = 0; q < 4; ++q)
        ab[(w * 32 + ri * 16 + lk * 4 + q) * 64 + nf * 16 + lr] =
            __float2bfloat16(acc[ri][nf][q]);
}

// ---------------- Kernel 3: combine partials, normalize, elu ----------------
__global__ __launch_bounds__(256) void k_combine(const __hip_bfloat16* __restrict__ accp,
                                                 const float* __restrict__ Zp,
                                                 float* __restrict__ out) {
  const int idx = blockIdx.x * 256 + threadIdx.x;
  const int r = idx >> 6, f = idx & 63;
  const int panel = r >> 7, rl = r & 127;
  float sum = 0.f, z = 0.f;
#pragma unroll
  for (int sp = 0; sp < SPLITS; ++sp) {
    const int b = panel * SPLITS + sp;
    sum += __bfloat162float(accp[(size_t)b * (BM * 64) + rl * 64 + f]);
    z += Zp[(size_t)b * BM + rl];
  }
  const float v = sum / z;
  out[idx] = (v > 0.f) ? v : expm1f(v);
}

extern "C" void kernel_launch(void* const* d_in, const int* in_sizes, int n_in,
                              void* d_out, int out_size, void* d_ws, size_t ws_size,
                              hipStream_t stream) {
  const float* h = (const float*)d_in[0];
  const int* adj = (const int*)d_in[1];
  const float* W = (const float*)d_in[2];
  const float* a = (const float*)d_in[3];
  float* out = (float*)d_out;

  const int npanel = NROW / BM;      // 64
  const int nblk = npanel * SPLITS;  // 1024

  char* p = (char*)d_ws;
  __hip_bfloat16* WhT = (__hip_bfloat16*)p;                  // 1 MB
  float* s = (float*)(p + 1048576);                          // 32 KB
  float* d = (float*)(p + 1048576 + 32768);                  // 32 KB
  float* Zp = (float*)(p + 1048576 + 65536);                 // 1024*128*4 = 512 KB
  __hip_bfloat16* accp =
      (__hip_bfloat16*)((char*)Zp + (size_t)nblk * BM * 4);  // 1024*128*64*2 = 16 MB

  hipLaunchKernelGGL(k_wh, dim3(NROW / 4), dim3(256), 0, stream, h, W, a, WhT, s, d);
  hipLaunchKernelGGL(k_main, dim3(nblk), dim3(256), 0, stream, adj, WhT, s, d, accp, Zp);
  hipLaunchKernelGGL(k_combine, dim3(out_size / 256), dim3(256), 0, stream, accp, Zp, out);
}